// Round 6
// baseline (215.083 us; speedup 1.0000x reference)
//
#include <hip/hip_runtime.h>

#define NB 32
#define NGT 100
#define NL 8400
#define NC 80
#define KTOP 13
#define TL 64
#define NITER 33  // ceil(NL/256)
#define VFL_BLOCKS 2048
#define SC_BLOCKS_X 33   // ceil(8400/256)
#define SC_BLOCKS (SC_BLOCKS_X * NB)

__device__ __forceinline__ float clamp0(float x) { return fmaxf(x, 0.f); }

__device__ __forceinline__ unsigned long long mkkey(float v, unsigned lowk) {
  return ((unsigned long long)__float_as_uint(v) << 32) | (unsigned long long)lowk;
}

// Block-reduce a double (256 threads); result valid on thread 0.
__device__ __forceinline__ double block_red(double v, double* sred) {
  for (int off = 32; off > 0; off >>= 1) v += __shfl_down(v, off);
  int wid = threadIdx.x >> 6;
  if ((threadIdx.x & 63) == 0) sred[wid] = v;
  __syncthreads();
  double r = 0.0;
  if (threadIdx.x == 0) r = sred[0] + sred[1] + sred[2] + sred[3];
  __syncthreads();
  return r;
}

// ---------------- Transpose: ps [b, l, c] -> pst [b, c, l] ----------------
__global__ __launch_bounds__(256) void transpose_kernel(
    const float* __restrict__ ps, float* __restrict__ pst)
{
  __shared__ float tile[TL][NC + 1];
  const int b = blockIdx.y;
  const int l0 = blockIdx.x * TL;
  const int nl = min(TL, NL - l0);
  for (int i = threadIdx.x; i < nl * 20; i += 256) {
    int r = i / 20, cv = i % 20;
    float4 v = ((const float4*)(ps + ((size_t)b * NL + l0 + r) * NC))[cv];
    tile[r][cv * 4 + 0] = v.x; tile[r][cv * 4 + 1] = v.y;
    tile[r][cv * 4 + 2] = v.z; tile[r][cv * 4 + 3] = v.w;
  }
  __syncthreads();
  for (int i = threadIdx.x; i < NC * TL; i += 256) {
    int c = i >> 6, r = i & 63;
    if (r < nl)
      pst[((size_t)b * NC + c) * NL + l0 + r] = tile[r][c];
  }
}

// ---- Kernel A: per-(b,n) metric; top-13 via per-lane top-1 + rescan --------
__global__ __launch_bounds__(256) void topk_kernel(
    const float* __restrict__ ps, const float* __restrict__ pst,
    const float* __restrict__ pb, const float* __restrict__ ap,
    const int* __restrict__ gl, const float* __restrict__ gtb,
    int* __restrict__ topk_out)
{
  __shared__ unsigned long long wred[2][4];
  const int bn = blockIdx.x;
  const int b = bn / NGT;
  const float gx1 = gtb[bn * 4 + 0], gy1 = gtb[bn * 4 + 1];
  const float gx2 = gtb[bn * 4 + 2], gy2 = gtb[bn * 4 + 3];
  const int cls = gl[bn];
  const float ga = clamp0(gx2 - gx1) * clamp0(gy2 - gy1);
  const float4* pbb = (const float4*)pb + (size_t)b * NL;
  const float* psb = ps + (size_t)b * NL * NC;
  const float* scp = pst ? pst + ((size_t)b * NC + cls) * NL : nullptr;
  const float2* apb = (const float2*)ap;
  const unsigned baselow = 0xFFFFFFFFu - threadIdx.x;  // ~l at i=0

  // Pass 1: metric for this lane's 33 strided anchors -> registers.
  float v[NITER];
#pragma unroll
  for (int i = 0; i < NITER; ++i) {
    const int l = (int)threadIdx.x + 256 * i;
    if (i < NITER - 1 || l < NL) {
      float4 p = pbb[l];
      float2 a = apb[l];
      float sc = scp ? scp[l] : psb[(size_t)l * NC + cls];
      float ox = fminf(p.z, gx2) - fmaxf(p.x, gx1);
      float oy = fminf(p.w, gy2) - fmaxf(p.y, gy1);
      float ov = clamp0(ox) * clamp0(oy);
      float pa = clamp0(p.z - p.x) * clamp0(p.w - p.y);
      float iou = ov * __builtin_amdgcn_rcpf(ga + pa - ov + 1e-9f);
      bool ins = fminf(fminf(a.x - gx1, a.y - gy1),
                       fminf(gx2 - a.x, gy2 - a.y)) > 1e-9f;
      float i2 = iou * iou;
      v[i] = ins ? sc * i2 * i2 * i2 : 0.f;
    } else {
      v[i] = 0.f;  // paired with lowk=0 below -> key 0, never selected
    }
  }

  // Per-lane best key (value desc, index asc; key = v_bits<<32 | ~l).
  unsigned long long best = 0ull;
#pragma unroll
  for (int i = 0; i < NITER; ++i) {
    const int l = (int)threadIdx.x + 256 * i;
    unsigned lowk = (i < NITER - 1 || l < NL) ? (baselow - 256u * i) : 0u;
    unsigned long long k = mkkey(v[i], lowk);
    best = (k > best) ? k : best;
  }

  // 13 rounds: block max of lane-bests; unique winner rescans below W.
  const int wid = threadIdx.x >> 6;
  for (int k = 0; k < KTOP; ++k) {
    unsigned long long m = best;
    for (int off = 32; off > 0; off >>= 1) {
      unsigned long long o = __shfl_down(m, off);
      if (o > m) m = o;
    }
    if ((threadIdx.x & 63) == 0) wred[k & 1][wid] = m;
    __syncthreads();
    unsigned long long W = wred[k & 1][0];
    if (wred[k & 1][1] > W) W = wred[k & 1][1];
    if (wred[k & 1][2] > W) W = wred[k & 1][2];
    if (wred[k & 1][3] > W) W = wred[k & 1][3];
    if (threadIdx.x == 0)
      topk_out[bn * KTOP + k] =
          (int)(0xFFFFFFFFu - (unsigned)(W & 0xFFFFFFFFull));
    if (best == W) {  // exactly one lane (keys unique, W > 0 always)
      unsigned long long nb = 0ull;
#pragma unroll
      for (int i = 0; i < NITER; ++i) {
        const int l = (int)threadIdx.x + 256 * i;
        unsigned lowk = (i < NITER - 1 || l < NL) ? (baselow - 256u * i) : 0u;
        unsigned long long kk = mkkey(v[i], lowk);
        if (kk < W && kk > nb) nb = kk;
      }
      best = nb;
    }
  }
}

// ------------- Kernel B: per-(b,l) assignment (n*, align*, iou*) -------------
__global__ __launch_bounds__(256) void assign_kernel(
    const float* __restrict__ ps, const float* __restrict__ pb,
    const float* __restrict__ ap, const int* __restrict__ gl,
    const float* __restrict__ gtb, const float* __restrict__ pad,
    const int* __restrict__ topk, int* __restrict__ nstar,
    float* __restrict__ astar, unsigned* __restrict__ maxm,
    unsigned* __restrict__ maxi)
{
  __shared__ float4 sgt[NGT];
  __shared__ int sgl[NGT];
  __shared__ float spad[NGT];
  __shared__ int stopk[NGT * KTOP];
  const int b = blockIdx.y;
  for (int i = threadIdx.x; i < NGT; i += 256) {
    sgt[i] = ((const float4*)gtb)[b * NGT + i];
    sgl[i] = gl[b * NGT + i];
    spad[i] = pad[b * NGT + i];
  }
  for (int i = threadIdx.x; i < NGT * KTOP; i += 256)
    stopk[i] = topk[b * NGT * KTOP + i];
  __syncthreads();

  const int l = blockIdx.x * 256 + threadIdx.x;
  if (l >= NL) return;

  float4 p = ((const float4*)pb)[(size_t)b * NL + l];
  float2 a = ((const float2*)ap)[l];
  float pa = clamp0(p.z - p.x) * clamp0(p.w - p.y);

  int mps = 0, n_single = -1, max_n = 0;
  float iou_single = 0.f, max_iou = -1.f;
  for (int n = 0; n < NGT; ++n) {
    float4 g = sgt[n];
    float ox = fminf(p.z, g.z) - fmaxf(p.x, g.x);
    float oy = fminf(p.w, g.w) - fmaxf(p.y, g.y);
    float ov = clamp0(ox) * clamp0(oy);
    float ga = clamp0(g.z - g.x) * clamp0(g.w - g.y);
    float iou = ov / (ga + pa - ov + 1e-9f);
    if (iou > max_iou) { max_iou = iou; max_n = n; }  // argmax over ALL n (incl. pad)
    bool ins = fminf(fminf(a.x - g.x, a.y - g.y),
                     fminf(g.z - a.x, g.w - a.y)) > 1e-9f;
    if (ins && spad[n] != 0.f) {
      bool hit = false;
#pragma unroll
      for (int k = 0; k < KTOP; ++k) hit |= (stopk[n * KTOP + k] == l);
      if (hit) { mps++; n_single = n; iou_single = iou; }
    }
  }

  int ns; float iou_s;
  if (mps == 0)      { ns = -1;       iou_s = 0.f; }
  else if (mps == 1) { ns = n_single; iou_s = iou_single; }
  else               { ns = max_n;    iou_s = max_iou; }  // is_max_iou replacement

  float al_s = 0.f;
  if (ns >= 0) {
    float sc = ps[((size_t)b * NL + l) * NC + sgl[ns]];
    float i2 = iou_s * iou_s;
    al_s = sc * i2 * i2 * i2;
    atomicMax(&maxm[b * NGT + ns], __float_as_uint(al_s));
    atomicMax(&maxi[b * NGT + ns], __float_as_uint(iou_s));
  }
  nstar[b * NL + l] = ns;
  astar[b * NL + l] = al_s;
}

// ------- Kernel C1: per-(b,l) scale/class + GIoU term; per-block partials ---
__global__ __launch_bounds__(256) void scale_kernel(
    const float* __restrict__ pb, const float* __restrict__ gtb,
    const int* __restrict__ gl, const int* __restrict__ nstar,
    const float* __restrict__ astar, const unsigned* __restrict__ maxm,
    const unsigned* __restrict__ maxi, float* __restrict__ scale_arr,
    int* __restrict__ jcls, double* __restrict__ part_sc)
{
  __shared__ double sred[4];
  const int b = blockIdx.y;
  const int l = blockIdx.x * 256 + threadIdx.x;
  double isum = 0.0, as = 0.0;
  if (l < NL) {
    int ns = nstar[b * NL + l];
    float scale = 0.f;
    int j = NC;
    if (ns >= 0) {
      float mm = __uint_as_float(maxm[b * NGT + ns]);
      float mi = __uint_as_float(maxi[b * NGT + ns]);
      scale = astar[b * NL + l] / (mm + 1e-9f) * mi;
      j = gl[b * NGT + ns];
      as = (double)scale;
      float4 p = ((const float4*)pb)[(size_t)b * NL + l];
      float4 g = ((const float4*)gtb)[b * NGT + ns];
      float x1 = fmaxf(p.x, g.x), y1 = fmaxf(p.y, g.y);
      float x2 = fminf(p.z, g.z), y2 = fminf(p.w, g.w);
      float ov = clamp0(x2 - x1) * clamp0(y2 - y1);
      float pa = clamp0(p.z - p.x) * clamp0(p.w - p.y);
      float ga = clamp0(g.z - g.x) * clamp0(g.w - g.y);
      float un = pa + ga - ov + 1e-10f;
      float iou = ov / un;
      float cx1 = fminf(p.x, g.x), cy1 = fminf(p.y, g.y);
      float cx2 = fmaxf(p.z, g.z), cy2 = fmaxf(p.w, g.w);
      float cc = clamp0(cx2 - cx1) * clamp0(cy2 - cy1) + 1e-10f;
      float gi = 1.f - (iou - (cc - un) / cc);
      isum = (double)(gi * scale);
    }
    scale_arr[b * NL + l] = scale;
    jcls[b * NL + l] = j;
  }
  double r0 = block_red(isum, sred);
  double r1 = block_red(as, sred);
  if (threadIdx.x == 0) {
    int blk = blockIdx.y * gridDim.x + blockIdx.x;
    part_sc[blk * 2 + 0] = r0;
    part_sc[blk * 2 + 1] = r1;
  }
}

// ---------- Kernel C2: coalesced VFL-BCE, grid-stride, block partials -------
__global__ __launch_bounds__(256) void vfl_kernel(
    const float* __restrict__ ps, const float* __restrict__ scale_arr,
    const int* __restrict__ jcls, double* __restrict__ part_vfl)
{
  __shared__ double sred[4];
  const unsigned total4 = (unsigned)NB * NL * 20;  // 5,376,000 float4 units
  double cs = 0.0;
  for (unsigned gid = blockIdx.x * 256 + threadIdx.x; gid < total4;
       gid += (unsigned)gridDim.x * 256) {
    const unsigned row = gid / 20;
    const int c0 = (int)(gid % 20) * 4;
    float4 s4 = ((const float4*)ps)[gid];
    float scale = scale_arr[row];
    int j = jcls[row];
    float sv[4] = {s4.x, s4.y, s4.z, s4.w};
    float csum = 0.f;
#pragma unroll
    for (int u = 0; u < 4; ++u) {
      float s = sv[u];
      float pcl = fminf(fmaxf(s, 1e-9f), 1.f - 1e-9f);
      float lp1 = log1pf(-pcl);
      if (c0 + u == j)
        csum += -(scale * logf(pcl) + (1.f - scale) * lp1) * scale;
      else
        csum += -lp1 * 0.75f * s * s;
    }
    cs += (double)csum;
  }
  double r = block_red(cs, sred);
  if (threadIdx.x == 0) part_vfl[blockIdx.x] = r;
}

// ---------------- Final: reduce partials, emit scalar ----------------------
__global__ __launch_bounds__(256) void fin_kernel(
    const double* __restrict__ part_vfl, const double* __restrict__ part_sc,
    float* __restrict__ out)
{
  __shared__ double sred[4];
  double cls = 0.0, isum = 0.0, as = 0.0;
  for (int i = threadIdx.x; i < VFL_BLOCKS; i += 256) cls += part_vfl[i];
  for (int i = threadIdx.x; i < SC_BLOCKS; i += 256) {
    isum += part_sc[i * 2 + 0];
    as   += part_sc[i * 2 + 1];
  }
  cls  = block_red(cls, sred);
  isum = block_red(isum, sred);
  as   = block_red(as, sred);
  if (threadIdx.x == 0) {
    double s = as > 1.0 ? as : 1.0;
    out[0] = (float)((cls + 2.5 * isum) / s);
  }
}

// ---------------------------------------------------------------------------
extern "C" void kernel_launch(void* const* d_in, const int* in_sizes, int n_in,
                              void* d_out, int out_size, void* d_ws, size_t ws_size,
                              hipStream_t stream) {
  const float* ps  = (const float*)d_in[0];   // [32,8400,80]
  const float* pbx = (const float*)d_in[1];   // [32,8400,4]
  const float* ap  = (const float*)d_in[2];   // [8400,2]
  const int*   gl  = (const int*)d_in[3];     // [32,100,1]
  const float* gtb = (const float*)d_in[4];   // [32,100,4]
  const float* pad = (const float*)d_in[5];   // [32,100,1]

  char* ws = (char*)d_ws;
  const size_t OFF_MAXM  = 0;                                 // 3200 u32
  const size_t OFF_MAXI  = OFF_MAXM + 4ul * NB * NGT;         // 3200 u32
  const size_t OFF_TOPK  = OFF_MAXI + 4ul * NB * NGT;         // 41600 i32
  const size_t OFF_NSTAR = OFF_TOPK + 4ul * NB * NGT * KTOP;  // 268800 i32
  const size_t OFF_ASTAR = OFF_NSTAR + 4ul * NB * NL;         // 268800 f32
  const size_t OFF_SCALE = OFF_ASTAR + 4ul * NB * NL;         // 268800 f32
  const size_t OFF_JCLS  = OFF_SCALE + 4ul * NB * NL;         // 268800 i32
  const size_t OFF_PVFL  = OFF_JCLS + 4ul * NB * NL;          // 2048 f64
  const size_t OFF_PSC   = OFF_PVFL + 8ul * VFL_BLOCKS;       // 2112 f64
  const size_t OFF_PST   = OFF_PSC + 8ul * SC_BLOCKS * 2;     // 86 MB f32
  const size_t PST_BYTES = 4ul * NB * NC * NL;

  unsigned* maxm  = (unsigned*)(ws + OFF_MAXM);
  unsigned* maxi  = (unsigned*)(ws + OFF_MAXI);
  int*      topk  = (int*)(ws + OFF_TOPK);
  int*      nstar = (int*)(ws + OFF_NSTAR);
  float*    astar = (float*)(ws + OFF_ASTAR);
  float*    scale_arr = (float*)(ws + OFF_SCALE);
  int*      jcls  = (int*)(ws + OFF_JCLS);
  double*   pvfl  = (double*)(ws + OFF_PVFL);
  double*   psc   = (double*)(ws + OFF_PSC);
  float*    pst   = (ws_size >= OFF_PST + PST_BYTES) ? (float*)(ws + OFF_PST) : nullptr;

  hipMemsetAsync(ws, 0, OFF_TOPK, stream);  // zero maxm + maxi

  if (pst)
    hipLaunchKernelGGL(transpose_kernel, dim3((NL + TL - 1) / TL, NB), dim3(256),
                       0, stream, ps, pst);
  hipLaunchKernelGGL(topk_kernel, dim3(NB * NGT), dim3(256), 0, stream,
                     ps, pst, pbx, ap, gl, gtb, topk);
  hipLaunchKernelGGL(assign_kernel, dim3(SC_BLOCKS_X, NB), dim3(256), 0, stream,
                     ps, pbx, ap, gl, gtb, pad, topk, nstar, astar, maxm, maxi);
  hipLaunchKernelGGL(scale_kernel, dim3(SC_BLOCKS_X, NB), dim3(256), 0, stream,
                     pbx, gtb, gl, nstar, astar, maxm, maxi, scale_arr, jcls, psc);
  hipLaunchKernelGGL(vfl_kernel, dim3(VFL_BLOCKS), dim3(256), 0, stream,
                     ps, scale_arr, jcls, pvfl);
  hipLaunchKernelGGL(fin_kernel, dim3(1), dim3(256), 0, stream, pvfl, psc,
                     (float*)d_out);
}

// Round 7
// 177.821 us; speedup vs baseline: 1.2095x; 1.2095x over previous
//
#include <hip/hip_runtime.h>

#define NB 32
#define NGT 100
#define NL 8400
#define NC 80
#define KTOP 13
#define TL 64
#define NITER 33  // ceil(NL/256)
#define MAXC 512  // >= max positives per (b,n) (bound ~336)
#define VFL_BLOCKS 2048
#define SC_BLOCKS_X 33   // ceil(8400/256)
#define SC_BLOCKS (SC_BLOCKS_X * NB)

__device__ __forceinline__ float clamp0(float x) { return fmaxf(x, 0.f); }

__device__ __forceinline__ unsigned long long mkkey(float v, unsigned lowk) {
  return ((unsigned long long)__float_as_uint(v) << 32) | (unsigned long long)lowk;
}

// Block-reduce a double (256 threads); result valid on thread 0.
__device__ __forceinline__ double block_red(double v, double* sred) {
  for (int off = 32; off > 0; off >>= 1) v += __shfl_down(v, off);
  int wid = threadIdx.x >> 6;
  if ((threadIdx.x & 63) == 0) sred[wid] = v;
  __syncthreads();
  double r = 0.0;
  if (threadIdx.x == 0) r = sred[0] + sred[1] + sred[2] + sred[3];
  __syncthreads();
  return r;
}

// ---------------- Transpose: ps [b, l, c] -> pst [b, c, l] ----------------
__global__ __launch_bounds__(256) void transpose_kernel(
    const float* __restrict__ ps, float* __restrict__ pst)
{
  __shared__ float tile[TL][NC + 1];
  const int b = blockIdx.y;
  const int l0 = blockIdx.x * TL;
  const int nl = min(TL, NL - l0);
  for (int i = threadIdx.x; i < nl * 20; i += 256) {
    int r = i / 20, cv = i % 20;
    float4 v = ((const float4*)(ps + ((size_t)b * NL + l0 + r) * NC))[cv];
    tile[r][cv * 4 + 0] = v.x; tile[r][cv * 4 + 1] = v.y;
    tile[r][cv * 4 + 2] = v.z; tile[r][cv * 4 + 3] = v.w;
  }
  __syncthreads();
  for (int i = threadIdx.x; i < NC * TL; i += 256) {
    int c = i >> 6, r = i & 63;
    if (r < nl)
      pst[((size_t)b * NC + c) * NL + l0 + r] = tile[r][c];
  }
}

// ---- Kernel A: metric scan -> LDS compaction -> wave-0 top-13 merge -------
__global__ __launch_bounds__(256) void topk_kernel(
    const float* __restrict__ ps, const float* __restrict__ pst,
    const float* __restrict__ pb, const float* __restrict__ ap,
    const int* __restrict__ gl, const float* __restrict__ gtb,
    int* __restrict__ topk_out)
{
  __shared__ unsigned long long cand[MAXC];
  __shared__ unsigned long long zmask_s;
  __shared__ int cnt;
  const int bn = blockIdx.x;
  const int b = bn / NGT;
  const float gx1 = gtb[bn * 4 + 0], gy1 = gtb[bn * 4 + 1];
  const float gx2 = gtb[bn * 4 + 2], gy2 = gtb[bn * 4 + 3];
  const int cls = gl[bn];
  const float ga = clamp0(gx2 - gx1) * clamp0(gy2 - gy1);
  const float4* pbb = (const float4*)pb + (size_t)b * NL;
  const float* psb = ps + (size_t)b * NL * NC;
  const float* scp = pst ? pst + ((size_t)b * NC + cls) * NL : nullptr;
  const float2* apb = (const float2*)ap;

  if (threadIdx.x == 0) cnt = 0;
  __syncthreads();

  // Scan: positives -> LDS list; wave 0 records zero-mask of anchors 0..63.
  for (int i = 0; i < NITER; ++i) {
    const int l = (int)threadIdx.x + 256 * i;
    float v = 0.f;
    if (l < NL) {
      float4 p = pbb[l];
      float2 a = apb[l];
      float sc = scp ? scp[l] : psb[(size_t)l * NC + cls];
      float ox = fminf(p.z, gx2) - fmaxf(p.x, gx1);
      float oy = fminf(p.w, gy2) - fmaxf(p.y, gy1);
      float ov = clamp0(ox) * clamp0(oy);
      float pa = clamp0(p.z - p.x) * clamp0(p.w - p.y);
      float iou = ov * __builtin_amdgcn_rcpf(ga + pa - ov + 1e-9f);
      bool ins = fminf(fminf(a.x - gx1, a.y - gy1),
                       fminf(gx2 - a.x, gy2 - a.y)) > 1e-9f;
      float i2 = iou * iou;
      v = ins ? sc * i2 * i2 * i2 : 0.f;
    }
    if (i == 0 && threadIdx.x < 64) {
      unsigned long long zm = __ballot(v == 0.f);  // anchors 0..63
      if (threadIdx.x == 0) zmask_s = zm;
    }
    if (v > 0.f) {
      int idx = atomicAdd(&cnt, 1);
      if (idx < MAXC) cand[idx] = mkkey(v, 0xFFFFFFFFu - (unsigned)l);
    }
  }
  __syncthreads();

  // Merge: wave 0 only, no barriers. Lanes hold <=8 candidates in regs.
  if (threadIdx.x < 64) {
    const int n = min(cnt, MAXC);
    unsigned long long c[MAXC / 64];
#pragma unroll
    for (int j = 0; j < MAXC / 64; ++j) {
      int idx = (int)threadIdx.x + 64 * j;
      c[j] = (idx < n) ? cand[idx] : 0ull;
    }
    unsigned long long zm = zmask_s;  // uniform across lanes
    for (int k = 0; k < KTOP; ++k) {
      unsigned long long m = c[0];
#pragma unroll
      for (int j = 1; j < MAXC / 64; ++j) m = (c[j] > m) ? c[j] : m;
      for (int off = 1; off < 64; off <<= 1) {
        unsigned long long o = __shfl_xor(m, off);
        m = (o > m) ? o : m;
      }
      int outl;
      if (m != 0ull) {  // a positive candidate wins
#pragma unroll
        for (int j = 0; j < MAXC / 64; ++j)
          if (c[j] == m) c[j] = 0ull;
        outl = (int)(0xFFFFFFFFu - (unsigned)(m & 0xFFFFFFFFull));
      } else {          // pad with smallest-index zero-metric anchor
        outl = (int)(__ffsll((long long)zm) - 1);
        zm &= zm - 1;
      }
      if (threadIdx.x == 0) topk_out[bn * KTOP + k] = outl;
    }
  }
}

// ------------- Kernel B: per-(b,l) assignment (n*, align*, iou*) -------------
__global__ __launch_bounds__(256) void assign_kernel(
    const float* __restrict__ ps, const float* __restrict__ pb,
    const float* __restrict__ ap, const int* __restrict__ gl,
    const float* __restrict__ gtb, const float* __restrict__ pad,
    const int* __restrict__ topk, int* __restrict__ nstar,
    float* __restrict__ astar, unsigned* __restrict__ maxm,
    unsigned* __restrict__ maxi)
{
  __shared__ float4 sgt[NGT];
  __shared__ int sgl[NGT];
  __shared__ float spad[NGT];
  __shared__ int stopk[NGT * KTOP];
  const int b = blockIdx.y;
  for (int i = threadIdx.x; i < NGT; i += 256) {
    sgt[i] = ((const float4*)gtb)[b * NGT + i];
    sgl[i] = gl[b * NGT + i];
    spad[i] = pad[b * NGT + i];
  }
  for (int i = threadIdx.x; i < NGT * KTOP; i += 256)
    stopk[i] = topk[b * NGT * KTOP + i];
  __syncthreads();

  const int l = blockIdx.x * 256 + threadIdx.x;
  if (l >= NL) return;

  float4 p = ((const float4*)pb)[(size_t)b * NL + l];
  float2 a = ((const float2*)ap)[l];
  float pa = clamp0(p.z - p.x) * clamp0(p.w - p.y);

  int mps = 0, n_single = -1, max_n = 0;
  float iou_single = 0.f, max_iou = -1.f;
  for (int n = 0; n < NGT; ++n) {
    float4 g = sgt[n];
    float ox = fminf(p.z, g.z) - fmaxf(p.x, g.x);
    float oy = fminf(p.w, g.w) - fmaxf(p.y, g.y);
    float ov = clamp0(ox) * clamp0(oy);
    float ga = clamp0(g.z - g.x) * clamp0(g.w - g.y);
    float iou = ov / (ga + pa - ov + 1e-9f);
    if (iou > max_iou) { max_iou = iou; max_n = n; }  // argmax over ALL n (incl. pad)
    bool ins = fminf(fminf(a.x - g.x, a.y - g.y),
                     fminf(g.z - a.x, g.w - a.y)) > 1e-9f;
    if (ins && spad[n] != 0.f) {
      bool hit = false;
#pragma unroll
      for (int k = 0; k < KTOP; ++k) hit |= (stopk[n * KTOP + k] == l);
      if (hit) { mps++; n_single = n; iou_single = iou; }
    }
  }

  int ns; float iou_s;
  if (mps == 0)      { ns = -1;       iou_s = 0.f; }
  else if (mps == 1) { ns = n_single; iou_s = iou_single; }
  else               { ns = max_n;    iou_s = max_iou; }  // is_max_iou replacement

  float al_s = 0.f;
  if (ns >= 0) {
    float sc = ps[((size_t)b * NL + l) * NC + sgl[ns]];
    float i2 = iou_s * iou_s;
    al_s = sc * i2 * i2 * i2;
    atomicMax(&maxm[b * NGT + ns], __float_as_uint(al_s));
    atomicMax(&maxi[b * NGT + ns], __float_as_uint(iou_s));
  }
  nstar[b * NL + l] = ns;
  astar[b * NL + l] = al_s;
}

// ------- Kernel C1: per-(b,l) scale/class + GIoU term; per-block partials ---
__global__ __launch_bounds__(256) void scale_kernel(
    const float* __restrict__ pb, const float* __restrict__ gtb,
    const int* __restrict__ gl, const int* __restrict__ nstar,
    const float* __restrict__ astar, const unsigned* __restrict__ maxm,
    const unsigned* __restrict__ maxi, float* __restrict__ scale_arr,
    int* __restrict__ jcls, double* __restrict__ part_sc)
{
  __shared__ double sred[4];
  const int b = blockIdx.y;
  const int l = blockIdx.x * 256 + threadIdx.x;
  double isum = 0.0, as = 0.0;
  if (l < NL) {
    int ns = nstar[b * NL + l];
    float scale = 0.f;
    int j = NC;
    if (ns >= 0) {
      float mm = __uint_as_float(maxm[b * NGT + ns]);
      float mi = __uint_as_float(maxi[b * NGT + ns]);
      scale = astar[b * NL + l] / (mm + 1e-9f) * mi;
      j = gl[b * NGT + ns];
      as = (double)scale;
      float4 p = ((const float4*)pb)[(size_t)b * NL + l];
      float4 g = ((const float4*)gtb)[b * NGT + ns];
      float x1 = fmaxf(p.x, g.x), y1 = fmaxf(p.y, g.y);
      float x2 = fminf(p.z, g.z), y2 = fminf(p.w, g.w);
      float ov = clamp0(x2 - x1) * clamp0(y2 - y1);
      float pa = clamp0(p.z - p.x) * clamp0(p.w - p.y);
      float ga = clamp0(g.z - g.x) * clamp0(g.w - g.y);
      float un = pa + ga - ov + 1e-10f;
      float iou = ov / un;
      float cx1 = fminf(p.x, g.x), cy1 = fminf(p.y, g.y);
      float cx2 = fmaxf(p.z, g.z), cy2 = fmaxf(p.w, g.w);
      float cc = clamp0(cx2 - cx1) * clamp0(cy2 - cy1) + 1e-10f;
      float gi = 1.f - (iou - (cc - un) / cc);
      isum = (double)(gi * scale);
    }
    scale_arr[b * NL + l] = scale;
    jcls[b * NL + l] = j;
  }
  double r0 = block_red(isum, sred);
  double r1 = block_red(as, sred);
  if (threadIdx.x == 0) {
    int blk = blockIdx.y * gridDim.x + blockIdx.x;
    part_sc[blk * 2 + 0] = r0;
    part_sc[blk * 2 + 1] = r1;
  }
}

// ---------- Kernel C2: coalesced VFL-BCE, grid-stride, block partials -------
__global__ __launch_bounds__(256) void vfl_kernel(
    const float* __restrict__ ps, const float* __restrict__ scale_arr,
    const int* __restrict__ jcls, double* __restrict__ part_vfl)
{
  __shared__ double sred[4];
  const unsigned total4 = (unsigned)NB * NL * 20;  // 5,376,000 float4 units
  double cs = 0.0;
  for (unsigned gid = blockIdx.x * 256 + threadIdx.x; gid < total4;
       gid += (unsigned)gridDim.x * 256) {
    const unsigned row = gid / 20;
    const int c0 = (int)(gid % 20) * 4;
    float4 s4 = ((const float4*)ps)[gid];
    float scale = scale_arr[row];
    int j = jcls[row];
    float sv[4] = {s4.x, s4.y, s4.z, s4.w};
    float csum = 0.f;
#pragma unroll
    for (int u = 0; u < 4; ++u) {
      float s = sv[u];
      float pcl = fminf(fmaxf(s, 1e-9f), 1.f - 1e-9f);
      float lp1 = log1pf(-pcl);
      if (c0 + u == j)
        csum += -(scale * logf(pcl) + (1.f - scale) * lp1) * scale;
      else
        csum += -lp1 * 0.75f * s * s;
    }
    cs += (double)csum;
  }
  double r = block_red(cs, sred);
  if (threadIdx.x == 0) part_vfl[blockIdx.x] = r;
}

// ---------------- Final: reduce partials, emit scalar ----------------------
__global__ __launch_bounds__(256) void fin_kernel(
    const double* __restrict__ part_vfl, const double* __restrict__ part_sc,
    float* __restrict__ out)
{
  __shared__ double sred[4];
  double cls = 0.0, isum = 0.0, as = 0.0;
  for (int i = threadIdx.x; i < VFL_BLOCKS; i += 256) cls += part_vfl[i];
  for (int i = threadIdx.x; i < SC_BLOCKS; i += 256) {
    isum += part_sc[i * 2 + 0];
    as   += part_sc[i * 2 + 1];
  }
  cls  = block_red(cls, sred);
  isum = block_red(isum, sred);
  as   = block_red(as, sred);
  if (threadIdx.x == 0) {
    double s = as > 1.0 ? as : 1.0;
    out[0] = (float)((cls + 2.5 * isum) / s);
  }
}

// ---------------------------------------------------------------------------
extern "C" void kernel_launch(void* const* d_in, const int* in_sizes, int n_in,
                              void* d_out, int out_size, void* d_ws, size_t ws_size,
                              hipStream_t stream) {
  const float* ps  = (const float*)d_in[0];   // [32,8400,80]
  const float* pbx = (const float*)d_in[1];   // [32,8400,4]
  const float* ap  = (const float*)d_in[2];   // [8400,2]
  const int*   gl  = (const int*)d_in[3];     // [32,100,1]
  const float* gtb = (const float*)d_in[4];   // [32,100,4]
  const float* pad = (const float*)d_in[5];   // [32,100,1]

  char* ws = (char*)d_ws;
  const size_t OFF_MAXM  = 0;                                 // 3200 u32
  const size_t OFF_MAXI  = OFF_MAXM + 4ul * NB * NGT;         // 3200 u32
  const size_t OFF_TOPK  = OFF_MAXI + 4ul * NB * NGT;         // 41600 i32
  const size_t OFF_NSTAR = OFF_TOPK + 4ul * NB * NGT * KTOP;  // 268800 i32
  const size_t OFF_ASTAR = OFF_NSTAR + 4ul * NB * NL;         // 268800 f32
  const size_t OFF_SCALE = OFF_ASTAR + 4ul * NB * NL;         // 268800 f32
  const size_t OFF_JCLS  = OFF_SCALE + 4ul * NB * NL;         // 268800 i32
  const size_t OFF_PVFL  = OFF_JCLS + 4ul * NB * NL;          // 2048 f64
  const size_t OFF_PSC   = OFF_PVFL + 8ul * VFL_BLOCKS;       // 2112 f64
  const size_t OFF_PST   = OFF_PSC + 8ul * SC_BLOCKS * 2;     // 86 MB f32
  const size_t PST_BYTES = 4ul * NB * NC * NL;

  unsigned* maxm  = (unsigned*)(ws + OFF_MAXM);
  unsigned* maxi  = (unsigned*)(ws + OFF_MAXI);
  int*      topk  = (int*)(ws + OFF_TOPK);
  int*      nstar = (int*)(ws + OFF_NSTAR);
  float*    astar = (float*)(ws + OFF_ASTAR);
  float*    scale_arr = (float*)(ws + OFF_SCALE);
  int*      jcls  = (int*)(ws + OFF_JCLS);
  double*   pvfl  = (double*)(ws + OFF_PVFL);
  double*   psc   = (double*)(ws + OFF_PSC);
  float*    pst   = (ws_size >= OFF_PST + PST_BYTES) ? (float*)(ws + OFF_PST) : nullptr;

  hipMemsetAsync(ws, 0, OFF_TOPK, stream);  // zero maxm + maxi

  if (pst)
    hipLaunchKernelGGL(transpose_kernel, dim3((NL + TL - 1) / TL, NB), dim3(256),
                       0, stream, ps, pst);
  hipLaunchKernelGGL(topk_kernel, dim3(NB * NGT), dim3(256), 0, stream,
                     ps, pst, pbx, ap, gl, gtb, topk);
  hipLaunchKernelGGL(assign_kernel, dim3(SC_BLOCKS_X, NB), dim3(256), 0, stream,
                     ps, pbx, ap, gl, gtb, pad, topk, nstar, astar, maxm, maxi);
  hipLaunchKernelGGL(scale_kernel, dim3(SC_BLOCKS_X, NB), dim3(256), 0, stream,
                     pbx, gtb, gl, nstar, astar, maxm, maxi, scale_arr, jcls, psc);
  hipLaunchKernelGGL(vfl_kernel, dim3(VFL_BLOCKS), dim3(256), 0, stream,
                     ps, scale_arr, jcls, pvfl);
  hipLaunchKernelGGL(fin_kernel, dim3(1), dim3(256), 0, stream, pvfl, psc,
                     (float*)d_out);
}

// Round 8
// 118.869 us; speedup vs baseline: 1.8094x; 1.4959x over previous
//
#include <hip/hip_runtime.h>

#define NB 32
#define NGT 100
#define NL 8400
#define NC 80
#define KTOP 13
#define NITER 33  // ceil(NL/256)
#define MAXC 512  // >= max inside-box anchors per (b,n) (bound ~395)
#define VFL_BLOCKS 2048
#define SC_BLOCKS_X 33   // ceil(8400/256)
#define SC_BLOCKS (SC_BLOCKS_X * NB)
#define LN2F 0.6931471805599453f

__device__ __forceinline__ float clamp0(float x) { return fmaxf(x, 0.f); }

__device__ __forceinline__ unsigned long long mkkey(float v, unsigned lowk) {
  return ((unsigned long long)__float_as_uint(v) << 32) | (unsigned long long)lowk;
}

// Block-reduce a double (256 threads); result valid on thread 0.
__device__ __forceinline__ double block_red(double v, double* sred) {
  for (int off = 32; off > 0; off >>= 1) v += __shfl_down(v, off);
  int wid = threadIdx.x >> 6;
  if ((threadIdx.x & 63) == 0) sred[wid] = v;
  __syncthreads();
  double r = 0.0;
  if (threadIdx.x == 0) r = sred[0] + sred[1] + sred[2] + sred[3];
  __syncthreads();
  return r;
}

// ---- Kernel A: iou scan -> compaction -> score gather -> wave-0 merge -----
__global__ __launch_bounds__(256) void topk_kernel(
    const float* __restrict__ ps, const float* __restrict__ pb,
    const float* __restrict__ ap, const int* __restrict__ gl,
    const float* __restrict__ gtb, int* __restrict__ topk_out)
{
  __shared__ unsigned long long cand[MAXC];
  __shared__ unsigned zmask[2];
  __shared__ int cnt;
  const int bn = blockIdx.x;
  const int b = bn / NGT;
  const float gx1 = gtb[bn * 4 + 0], gy1 = gtb[bn * 4 + 1];
  const float gx2 = gtb[bn * 4 + 2], gy2 = gtb[bn * 4 + 3];
  const int cls = gl[bn];
  const float ga = clamp0(gx2 - gx1) * clamp0(gy2 - gy1);
  const float4* pbb = (const float4*)pb + (size_t)b * NL;
  const float* psb = ps + (size_t)b * NL * NC;
  const float2* apb = (const float2*)ap;

  if (threadIdx.x == 0) cnt = 0;
  __syncthreads();

  // Phase 1: inside-box anchors with iou>0 -> LDS list (no score reads).
  for (int i = 0; i < NITER; ++i) {
    const int l = (int)threadIdx.x + 256 * i;
    bool pos = false;
    float iou = 0.f;
    if (l < NL) {
      float4 p = pbb[l];
      float2 a = apb[l];
      float ox = fminf(p.z, gx2) - fmaxf(p.x, gx1);
      float oy = fminf(p.w, gy2) - fmaxf(p.y, gy1);
      float ov = clamp0(ox) * clamp0(oy);
      float pa = clamp0(p.z - p.x) * clamp0(p.w - p.y);
      iou = ov * __builtin_amdgcn_rcpf(ga + pa - ov + 1e-9f);
      bool ins = fminf(fminf(a.x - gx1, a.y - gy1),
                       fminf(gx2 - a.x, gy2 - a.y)) > 1e-9f;
      pos = ins && (iou > 0.f);
    }
    if (i == 0 && threadIdx.x < 64) {
      unsigned long long zm = __ballot(!pos);  // anchors 0..63 with metric 0
      if (threadIdx.x == 0) { zmask[0] = (unsigned)zm; zmask[1] = (unsigned)(zm >> 32); }
    }
    if (pos) {
      int idx = atomicAdd(&cnt, 1);
      if (idx < MAXC)
        cand[idx] = ((unsigned long long)__float_as_uint(iou) << 32) |
                    (unsigned long long)(0xFFFFFFFFu - (unsigned)l);
    }
  }
  __syncthreads();

  // Phase 2: gather score for compacted anchors only; finalize key v=sc*iou^6.
  const int n = min(cnt, MAXC);
  for (int idx = threadIdx.x; idx < n; idx += 256) {
    unsigned long long e = cand[idx];
    unsigned lowk = (unsigned)e;
    int l = (int)(0xFFFFFFFFu - lowk);
    float iou = __uint_as_float((unsigned)(e >> 32));
    float sc = psb[(size_t)l * NC + cls];
    float i2 = iou * iou;
    float v = sc * i2 * i2 * i2;
    if (v > 0.f) {
      cand[idx] = mkkey(v, lowk);
    } else {               // underflow: metric exactly 0 -> zero-tie set
      cand[idx] = 0ull;
      if (l < 64) atomicOr(&zmask[l >> 5], 1u << (l & 31));
    }
  }
  __syncthreads();

  // Merge: wave 0 only, no barriers. Lanes hold <=8 candidates in regs.
  if (threadIdx.x < 64) {
    unsigned long long c[MAXC / 64];
#pragma unroll
    for (int j = 0; j < MAXC / 64; ++j) {
      int idx = (int)threadIdx.x + 64 * j;
      c[j] = (idx < n) ? cand[idx] : 0ull;
    }
    unsigned long long zm = ((unsigned long long)zmask[1] << 32) | zmask[0];
    for (int k = 0; k < KTOP; ++k) {
      unsigned long long m = c[0];
#pragma unroll
      for (int j = 1; j < MAXC / 64; ++j) m = (c[j] > m) ? c[j] : m;
      for (int off = 1; off < 64; off <<= 1) {
        unsigned long long o = __shfl_xor(m, off);
        m = (o > m) ? o : m;
      }
      int outl;
      if (m != 0ull) {  // a positive candidate wins
#pragma unroll
        for (int j = 0; j < MAXC / 64; ++j)
          if (c[j] == m) c[j] = 0ull;
        outl = (int)(0xFFFFFFFFu - (unsigned)(m & 0xFFFFFFFFull));
      } else {          // pad with smallest-index zero-metric anchor
        outl = (int)(__ffsll((long long)zm) - 1);
        zm &= zm - 1;
      }
      if (threadIdx.x == 0) topk_out[bn * KTOP + k] = outl;
    }
  }
}

// ------------- Kernel B: per-(b,l) assignment (n*, align*, iou*) -------------
__global__ __launch_bounds__(256) void assign_kernel(
    const float* __restrict__ ps, const float* __restrict__ pb,
    const float* __restrict__ ap, const int* __restrict__ gl,
    const float* __restrict__ gtb, const float* __restrict__ pad,
    const int* __restrict__ topk, int* __restrict__ nstar,
    float* __restrict__ astar, unsigned* __restrict__ maxm,
    unsigned* __restrict__ maxi)
{
  __shared__ float4 sgt[NGT];
  __shared__ int sgl[NGT];
  __shared__ float spad[NGT];
  __shared__ int stopk[NGT * KTOP];
  const int b = blockIdx.y;
  for (int i = threadIdx.x; i < NGT; i += 256) {
    sgt[i] = ((const float4*)gtb)[b * NGT + i];
    sgl[i] = gl[b * NGT + i];
    spad[i] = pad[b * NGT + i];
  }
  for (int i = threadIdx.x; i < NGT * KTOP; i += 256)
    stopk[i] = topk[b * NGT * KTOP + i];
  __syncthreads();

  const int l = blockIdx.x * 256 + threadIdx.x;
  if (l >= NL) return;

  float4 p = ((const float4*)pb)[(size_t)b * NL + l];
  float2 a = ((const float2*)ap)[l];
  float pa = clamp0(p.z - p.x) * clamp0(p.w - p.y);

  int mps = 0, n_single = -1, max_n = 0;
  float iou_single = 0.f, max_iou = -1.f;
  for (int n = 0; n < NGT; ++n) {
    float4 g = sgt[n];
    float ox = fminf(p.z, g.z) - fmaxf(p.x, g.x);
    float oy = fminf(p.w, g.w) - fmaxf(p.y, g.y);
    float ov = clamp0(ox) * clamp0(oy);
    float ga = clamp0(g.z - g.x) * clamp0(g.w - g.y);
    float iou = ov / (ga + pa - ov + 1e-9f);
    if (iou > max_iou) { max_iou = iou; max_n = n; }  // argmax over ALL n (incl. pad)
    bool ins = fminf(fminf(a.x - g.x, a.y - g.y),
                     fminf(g.z - a.x, g.w - a.y)) > 1e-9f;
    if (ins && spad[n] != 0.f) {
      bool hit = false;
#pragma unroll
      for (int k = 0; k < KTOP; ++k) hit |= (stopk[n * KTOP + k] == l);
      if (hit) { mps++; n_single = n; iou_single = iou; }
    }
  }

  int ns; float iou_s;
  if (mps == 0)      { ns = -1;       iou_s = 0.f; }
  else if (mps == 1) { ns = n_single; iou_s = iou_single; }
  else               { ns = max_n;    iou_s = max_iou; }  // is_max_iou replacement

  float al_s = 0.f;
  if (ns >= 0) {
    float sc = ps[((size_t)b * NL + l) * NC + sgl[ns]];
    float i2 = iou_s * iou_s;
    al_s = sc * i2 * i2 * i2;
    atomicMax(&maxm[b * NGT + ns], __float_as_uint(al_s));
    atomicMax(&maxi[b * NGT + ns], __float_as_uint(iou_s));
  }
  nstar[b * NL + l] = ns;
  astar[b * NL + l] = al_s;
}

// ------- Kernel C1: per-(b,l) scale/class + GIoU term; per-block partials ---
__global__ __launch_bounds__(256) void scale_kernel(
    const float* __restrict__ pb, const float* __restrict__ gtb,
    const int* __restrict__ gl, const int* __restrict__ nstar,
    const float* __restrict__ astar, const unsigned* __restrict__ maxm,
    const unsigned* __restrict__ maxi, float* __restrict__ scale_arr,
    int* __restrict__ jcls, double* __restrict__ part_sc)
{
  __shared__ double sred[4];
  const int b = blockIdx.y;
  const int l = blockIdx.x * 256 + threadIdx.x;
  double isum = 0.0, as = 0.0;
  if (l < NL) {
    int ns = nstar[b * NL + l];
    float scale = 0.f;
    int j = NC;
    if (ns >= 0) {
      float mm = __uint_as_float(maxm[b * NGT + ns]);
      float mi = __uint_as_float(maxi[b * NGT + ns]);
      scale = astar[b * NL + l] / (mm + 1e-9f) * mi;
      j = gl[b * NGT + ns];
      as = (double)scale;
      float4 p = ((const float4*)pb)[(size_t)b * NL + l];
      float4 g = ((const float4*)gtb)[b * NGT + ns];
      float x1 = fmaxf(p.x, g.x), y1 = fmaxf(p.y, g.y);
      float x2 = fminf(p.z, g.z), y2 = fminf(p.w, g.w);
      float ov = clamp0(x2 - x1) * clamp0(y2 - y1);
      float pa = clamp0(p.z - p.x) * clamp0(p.w - p.y);
      float ga = clamp0(g.z - g.x) * clamp0(g.w - g.y);
      float un = pa + ga - ov + 1e-10f;
      float iou = ov / un;
      float cx1 = fminf(p.x, g.x), cy1 = fminf(p.y, g.y);
      float cx2 = fmaxf(p.z, g.z), cy2 = fmaxf(p.w, g.w);
      float cc = clamp0(cx2 - cx1) * clamp0(cy2 - cy1) + 1e-10f;
      float gi = 1.f - (iou - (cc - un) / cc);
      isum = (double)(gi * scale);
    }
    scale_arr[b * NL + l] = scale;
    jcls[b * NL + l] = j;
  }
  double r0 = block_red(isum, sred);
  double r1 = block_red(as, sred);
  if (threadIdx.x == 0) {
    int blk = blockIdx.y * gridDim.x + blockIdx.x;
    part_sc[blk * 2 + 0] = r0;
    part_sc[blk * 2 + 1] = r1;
  }
}

// ---------- Kernel C2: coalesced VFL-BCE (fast hw log), block partials ------
__global__ __launch_bounds__(256) void vfl_kernel(
    const float* __restrict__ ps, const float* __restrict__ scale_arr,
    const int* __restrict__ jcls, double* __restrict__ part_vfl)
{
  __shared__ double sred[4];
  const unsigned total4 = (unsigned)NB * NL * 20;  // 5,376,000 float4 units
  double cs = 0.0;
  for (unsigned gid = blockIdx.x * 256 + threadIdx.x; gid < total4;
       gid += (unsigned)gridDim.x * 256) {
    const unsigned row = gid / 20;
    const int c0 = (int)(gid % 20) * 4;
    float4 s4 = ((const float4*)ps)[gid];
    float scale = scale_arr[row];
    int j = jcls[row];
    float sv[4] = {s4.x, s4.y, s4.z, s4.w};
    float csum = 0.f;
#pragma unroll
    for (int u = 0; u < 4; ++u) {
      float s = sv[u];
      float pcl = fminf(fmaxf(s, 1e-9f), 1.f - 1e-9f);
      float lp1 = __log2f(1.f - pcl) * LN2F;   // log1p(-p), hw v_log_f32
      if (c0 + u == j)
        csum += -(scale * (__log2f(pcl) * LN2F) + (1.f - scale) * lp1) * scale;
      else
        csum += -lp1 * 0.75f * s * s;
    }
    cs += (double)csum;
  }
  double r = block_red(cs, sred);
  if (threadIdx.x == 0) part_vfl[blockIdx.x] = r;
}

// ---------------- Final: reduce partials, emit scalar ----------------------
__global__ __launch_bounds__(256) void fin_kernel(
    const double* __restrict__ part_vfl, const double* __restrict__ part_sc,
    float* __restrict__ out)
{
  __shared__ double sred[4];
  double cls = 0.0, isum = 0.0, as = 0.0;
  for (int i = threadIdx.x; i < VFL_BLOCKS; i += 256) cls += part_vfl[i];
  for (int i = threadIdx.x; i < SC_BLOCKS; i += 256) {
    isum += part_sc[i * 2 + 0];
    as   += part_sc[i * 2 + 1];
  }
  cls  = block_red(cls, sred);
  isum = block_red(isum, sred);
  as   = block_red(as, sred);
  if (threadIdx.x == 0) {
    double s = as > 1.0 ? as : 1.0;
    out[0] = (float)((cls + 2.5 * isum) / s);
  }
}

// ---------------------------------------------------------------------------
extern "C" void kernel_launch(void* const* d_in, const int* in_sizes, int n_in,
                              void* d_out, int out_size, void* d_ws, size_t ws_size,
                              hipStream_t stream) {
  const float* ps  = (const float*)d_in[0];   // [32,8400,80]
  const float* pbx = (const float*)d_in[1];   // [32,8400,4]
  const float* ap  = (const float*)d_in[2];   // [8400,2]
  const int*   gl  = (const int*)d_in[3];     // [32,100,1]
  const float* gtb = (const float*)d_in[4];   // [32,100,4]
  const float* pad = (const float*)d_in[5];   // [32,100,1]

  char* ws = (char*)d_ws;
  const size_t OFF_MAXM  = 0;                                 // 3200 u32
  const size_t OFF_MAXI  = OFF_MAXM + 4ul * NB * NGT;         // 3200 u32
  const size_t OFF_TOPK  = OFF_MAXI + 4ul * NB * NGT;         // 41600 i32
  const size_t OFF_NSTAR = OFF_TOPK + 4ul * NB * NGT * KTOP;  // 268800 i32
  const size_t OFF_ASTAR = OFF_NSTAR + 4ul * NB * NL;         // 268800 f32
  const size_t OFF_SCALE = OFF_ASTAR + 4ul * NB * NL;         // 268800 f32
  const size_t OFF_JCLS  = OFF_SCALE + 4ul * NB * NL;         // 268800 i32
  const size_t OFF_PVFL  = OFF_JCLS + 4ul * NB * NL;          // 2048 f64
  const size_t OFF_PSC   = OFF_PVFL + 8ul * VFL_BLOCKS;       // 2112 f64

  unsigned* maxm  = (unsigned*)(ws + OFF_MAXM);
  unsigned* maxi  = (unsigned*)(ws + OFF_MAXI);
  int*      topk  = (int*)(ws + OFF_TOPK);
  int*      nstar = (int*)(ws + OFF_NSTAR);
  float*    astar = (float*)(ws + OFF_ASTAR);
  float*    scale_arr = (float*)(ws + OFF_SCALE);
  int*      jcls  = (int*)(ws + OFF_JCLS);
  double*   pvfl  = (double*)(ws + OFF_PVFL);
  double*   psc   = (double*)(ws + OFF_PSC);

  hipMemsetAsync(ws, 0, OFF_TOPK, stream);  // zero maxm + maxi

  hipLaunchKernelGGL(topk_kernel, dim3(NB * NGT), dim3(256), 0, stream,
                     ps, pbx, ap, gl, gtb, topk);
  hipLaunchKernelGGL(assign_kernel, dim3(SC_BLOCKS_X, NB), dim3(256), 0, stream,
                     ps, pbx, ap, gl, gtb, pad, topk, nstar, astar, maxm, maxi);
  hipLaunchKernelGGL(scale_kernel, dim3(SC_BLOCKS_X, NB), dim3(256), 0, stream,
                     pbx, gtb, gl, nstar, astar, maxm, maxi, scale_arr, jcls, psc);
  hipLaunchKernelGGL(vfl_kernel, dim3(VFL_BLOCKS), dim3(256), 0, stream,
                     ps, scale_arr, jcls, pvfl);
  hipLaunchKernelGGL(fin_kernel, dim3(1), dim3(256), 0, stream, pvfl, psc,
                     (float*)d_out);
}

// Round 9
// 93.706 us; speedup vs baseline: 2.2953x; 1.2685x over previous
//
#include <hip/hip_runtime.h>

#define NB 32
#define NGT 100
#define NL 8400
#define NC 80
#define KTOP 13
#define MAXC 640  // >= max enumerated candidates per (b,n) (bound ~531)
#define VFL_BLOCKS 2048
#define SC_BLOCKS_X 33   // ceil(8400/256)
#define SC_BLOCKS (SC_BLOCKS_X * NB)
#define LN2F 0.6931471805599453f

__device__ __forceinline__ float clamp0(float x) { return fmaxf(x, 0.f); }

__device__ __forceinline__ unsigned long long mkkey(float v, unsigned lowk) {
  return ((unsigned long long)__float_as_uint(v) << 32) | (unsigned long long)lowk;
}

// Block-reduce a double (256 threads); result valid on thread 0.
__device__ __forceinline__ double block_red(double v, double* sred) {
  for (int off = 32; off > 0; off >>= 1) v += __shfl_down(v, off);
  int wid = threadIdx.x >> 6;
  if ((threadIdx.x & 63) == 0) sred[wid] = v;
  __syncthreads();
  double r = 0.0;
  if (threadIdx.x == 0) r = sred[0] + sred[1] + sred[2] + sred[3];
  __syncthreads();
  return r;
}

// conservative grid range for centers (c+0.5)*s inside (lo, hi)
__device__ __forceinline__ void grange(float lo, float hi, float s, int G,
                                       int& a0, int& an) {
  int c0 = max(0, (int)floorf(lo / s - 0.5f));
  int c1 = min(G - 1, (int)ceilf(hi / s - 0.5f));
  a0 = c0;
  an = max(0, c1 - c0 + 1);
}

// ---- Kernel A: candidate ENUMERATION (no full scan) -> wave-0 top-13 ------
__global__ __launch_bounds__(256) void topk_kernel(
    const float* __restrict__ ps, const float* __restrict__ pb,
    const int* __restrict__ gl, const float* __restrict__ gtb,
    int* __restrict__ topk_out)
{
  __shared__ unsigned long long cand[MAXC];
  __shared__ unsigned zmask[2];
  __shared__ int cnt;
  const int bn = blockIdx.x;
  const int b = bn / NGT;
  const float gx1 = gtb[bn * 4 + 0], gy1 = gtb[bn * 4 + 1];
  const float gx2 = gtb[bn * 4 + 2], gy2 = gtb[bn * 4 + 3];
  const int cls = gl[bn];
  const float ga = clamp0(gx2 - gx1) * clamp0(gy2 - gy1);
  const float4* pbb = (const float4*)pb + (size_t)b * NL;
  const float* psb = ps + (size_t)b * NL * NC;

  if (threadIdx.x == 0) cnt = 0;

  // Pass A (wave 0): zero-metric mask for anchors 0..63 (row 0 of s8 grid).
  if (threadIdx.x < 64) {
    const int l = (int)threadIdx.x;
    float4 p = pbb[l];
    float x = ((float)l + 0.5f) * 8.0f, y = 4.0f;
    float ox = fminf(p.z, gx2) - fmaxf(p.x, gx1);
    float oy = fminf(p.w, gy2) - fmaxf(p.y, gy1);
    float ov = clamp0(ox) * clamp0(oy);
    float pa = clamp0(p.z - p.x) * clamp0(p.w - p.y);
    float iou = ov * __builtin_amdgcn_rcpf(ga + pa - ov + 1e-9f);
    bool ins = fminf(fminf(x - gx1, y - gy1),
                     fminf(gx2 - x, gy2 - y)) > 1e-9f;
    bool pos = ins && (iou > 0.f);
    unsigned long long zm = __ballot(!pos);
    if (threadIdx.x == 0) { zmask[0] = (unsigned)zm; zmask[1] = (unsigned)(zm >> 32); }
  }
  __syncthreads();

  // Candidate windows per scale (identical scalars on all threads).
  int c8, nc8, r8, nr8, c16, nc16, r16, nr16, c32, nc32, r32, nr32;
  grange(gx1, gx2, 8.f, 80, c8, nc8);   grange(gy1, gy2, 8.f, 80, r8, nr8);
  grange(gx1, gx2, 16.f, 40, c16, nc16); grange(gy1, gy2, 16.f, 40, r16, nr16);
  grange(gx1, gx2, 32.f, 20, c32, nc32); grange(gy1, gy2, 32.f, 20, r32, nr32);
  const int t8 = nc8 * nr8, t16 = nc16 * nr16, t32 = nc32 * nr32;
  const int total = t8 + t16 + t32;

  // Phase 1: test enumerated candidates; positives -> LDS list.
  for (int idx = threadIdx.x; idx < total; idx += 256) {
    int l; float x, y;
    if (idx < t8) {
      int q = idx / nc8, cc = c8 + (idx - q * nc8), rr = r8 + q;
      l = rr * 80 + cc; x = ((float)cc + 0.5f) * 8.f; y = ((float)rr + 0.5f) * 8.f;
    } else if (idx < t8 + t16) {
      int id = idx - t8;
      int q = id / nc16, cc = c16 + (id - q * nc16), rr = r16 + q;
      l = 6400 + rr * 40 + cc; x = ((float)cc + 0.5f) * 16.f; y = ((float)rr + 0.5f) * 16.f;
    } else {
      int id = idx - t8 - t16;
      int q = id / nc32, cc = c32 + (id - q * nc32), rr = r32 + q;
      l = 8000 + rr * 20 + cc; x = ((float)cc + 0.5f) * 32.f; y = ((float)rr + 0.5f) * 32.f;
    }
    float4 p = pbb[l];
    float ox = fminf(p.z, gx2) - fmaxf(p.x, gx1);
    float oy = fminf(p.w, gy2) - fmaxf(p.y, gy1);
    float ov = clamp0(ox) * clamp0(oy);
    float pa = clamp0(p.z - p.x) * clamp0(p.w - p.y);
    float iou = ov * __builtin_amdgcn_rcpf(ga + pa - ov + 1e-9f);
    bool ins = fminf(fminf(x - gx1, y - gy1),
                     fminf(gx2 - x, gy2 - y)) > 1e-9f;
    if (ins && iou > 0.f) {
      int id2 = atomicAdd(&cnt, 1);
      if (id2 < MAXC)
        cand[id2] = ((unsigned long long)__float_as_uint(iou) << 32) |
                    (unsigned long long)(0xFFFFFFFFu - (unsigned)l);
    }
  }
  __syncthreads();

  // Phase 2: gather score for positives; finalize key v = sc * iou^6.
  const int n = min(cnt, MAXC);
  for (int idx = threadIdx.x; idx < n; idx += 256) {
    unsigned long long e = cand[idx];
    unsigned lowk = (unsigned)e;
    int l = (int)(0xFFFFFFFFu - lowk);
    float iou = __uint_as_float((unsigned)(e >> 32));
    float sc = psb[(size_t)l * NC + cls];
    float i2 = iou * iou;
    float v = sc * i2 * i2 * i2;
    if (v > 0.f) {
      cand[idx] = mkkey(v, lowk);
    } else {               // underflow: metric exactly 0 -> zero-tie set
      cand[idx] = 0ull;
      if (l < 64) atomicOr(&zmask[l >> 5], 1u << (l & 31));
    }
  }
  __syncthreads();

  // Merge: wave 0 only, no barriers. Lanes hold <=10 candidates in regs.
  if (threadIdx.x < 64) {
    unsigned long long c[MAXC / 64];
#pragma unroll
    for (int j = 0; j < MAXC / 64; ++j) {
      int idx = (int)threadIdx.x + 64 * j;
      c[j] = (idx < n) ? cand[idx] : 0ull;
    }
    unsigned long long zm = ((unsigned long long)zmask[1] << 32) | zmask[0];
    for (int k = 0; k < KTOP; ++k) {
      unsigned long long m = c[0];
#pragma unroll
      for (int j = 1; j < MAXC / 64; ++j) m = (c[j] > m) ? c[j] : m;
      for (int off = 1; off < 64; off <<= 1) {
        unsigned long long o = __shfl_xor(m, off);
        m = (o > m) ? o : m;
      }
      int outl;
      if (m != 0ull) {  // a positive candidate wins
#pragma unroll
        for (int j = 0; j < MAXC / 64; ++j)
          if (c[j] == m) c[j] = 0ull;
        outl = (int)(0xFFFFFFFFu - (unsigned)(m & 0xFFFFFFFFull));
      } else {          // pad with smallest-index zero-metric anchor
        outl = (int)(__ffsll((long long)zm) - 1);
        zm &= zm - 1;
      }
      if (threadIdx.x == 0) topk_out[bn * KTOP + k] = outl;
    }
  }
}

// ------------- Kernel B: per-(b,l) assignment (n*, align*, iou*) -------------
__global__ __launch_bounds__(256) void assign_kernel(
    const float* __restrict__ ps, const float* __restrict__ pb,
    const float* __restrict__ ap, const int* __restrict__ gl,
    const float* __restrict__ gtb, const float* __restrict__ pad,
    const int* __restrict__ topk, int* __restrict__ nstar,
    float* __restrict__ astar, unsigned* __restrict__ maxm,
    unsigned* __restrict__ maxi)
{
  __shared__ float4 sgt[NGT];
  __shared__ int sgl[NGT];
  __shared__ float spad[NGT];
  __shared__ int stopk[NGT * KTOP];
  const int b = blockIdx.y;
  for (int i = threadIdx.x; i < NGT; i += 256) {
    sgt[i] = ((const float4*)gtb)[b * NGT + i];
    sgl[i] = gl[b * NGT + i];
    spad[i] = pad[b * NGT + i];
  }
  for (int i = threadIdx.x; i < NGT * KTOP; i += 256)
    stopk[i] = topk[b * NGT * KTOP + i];
  __syncthreads();

  const int l = blockIdx.x * 256 + threadIdx.x;
  if (l >= NL) return;

  float4 p = ((const float4*)pb)[(size_t)b * NL + l];
  float2 a = ((const float2*)ap)[l];
  float pa = clamp0(p.z - p.x) * clamp0(p.w - p.y);

  int mps = 0, n_single = -1, max_n = 0;
  float iou_single = 0.f, max_iou = -1.f;
  for (int n = 0; n < NGT; ++n) {
    float4 g = sgt[n];
    float ox = fminf(p.z, g.z) - fmaxf(p.x, g.x);
    float oy = fminf(p.w, g.w) - fmaxf(p.y, g.y);
    float ov = clamp0(ox) * clamp0(oy);
    float ga = clamp0(g.z - g.x) * clamp0(g.w - g.y);
    float iou = ov / (ga + pa - ov + 1e-9f);
    if (iou > max_iou) { max_iou = iou; max_n = n; }  // argmax over ALL n (incl. pad)
    bool ins = fminf(fminf(a.x - g.x, a.y - g.y),
                     fminf(g.z - a.x, g.w - a.y)) > 1e-9f;
    if (ins && spad[n] != 0.f) {
      bool hit = false;
#pragma unroll
      for (int k = 0; k < KTOP; ++k) hit |= (stopk[n * KTOP + k] == l);
      if (hit) { mps++; n_single = n; iou_single = iou; }
    }
  }

  int ns; float iou_s;
  if (mps == 0)      { ns = -1;       iou_s = 0.f; }
  else if (mps == 1) { ns = n_single; iou_s = iou_single; }
  else               { ns = max_n;    iou_s = max_iou; }  // is_max_iou replacement

  float al_s = 0.f;
  if (ns >= 0) {
    float sc = ps[((size_t)b * NL + l) * NC + sgl[ns]];
    float i2 = iou_s * iou_s;
    al_s = sc * i2 * i2 * i2;
    atomicMax(&maxm[b * NGT + ns], __float_as_uint(al_s));
    atomicMax(&maxi[b * NGT + ns], __float_as_uint(iou_s));
  }
  nstar[b * NL + l] = ns;
  astar[b * NL + l] = al_s;
}

// ------- Kernel C1: per-(b,l) scale/class + GIoU term; per-block partials ---
__global__ __launch_bounds__(256) void scale_kernel(
    const float* __restrict__ pb, const float* __restrict__ gtb,
    const int* __restrict__ gl, const int* __restrict__ nstar,
    const float* __restrict__ astar, const unsigned* __restrict__ maxm,
    const unsigned* __restrict__ maxi, float* __restrict__ scale_arr,
    int* __restrict__ jcls, double* __restrict__ part_sc)
{
  __shared__ double sred[4];
  const int b = blockIdx.y;
  const int l = blockIdx.x * 256 + threadIdx.x;
  double isum = 0.0, as = 0.0;
  if (l < NL) {
    int ns = nstar[b * NL + l];
    float scale = 0.f;
    int j = NC;
    if (ns >= 0) {
      float mm = __uint_as_float(maxm[b * NGT + ns]);
      float mi = __uint_as_float(maxi[b * NGT + ns]);
      scale = astar[b * NL + l] / (mm + 1e-9f) * mi;
      j = gl[b * NGT + ns];
      as = (double)scale;
      float4 p = ((const float4*)pb)[(size_t)b * NL + l];
      float4 g = ((const float4*)gtb)[b * NGT + ns];
      float x1 = fmaxf(p.x, g.x), y1 = fmaxf(p.y, g.y);
      float x2 = fminf(p.z, g.z), y2 = fminf(p.w, g.w);
      float ov = clamp0(x2 - x1) * clamp0(y2 - y1);
      float pa = clamp0(p.z - p.x) * clamp0(p.w - p.y);
      float ga = clamp0(g.z - g.x) * clamp0(g.w - g.y);
      float un = pa + ga - ov + 1e-10f;
      float iou = ov / un;
      float cx1 = fminf(p.x, g.x), cy1 = fminf(p.y, g.y);
      float cx2 = fmaxf(p.z, g.z), cy2 = fmaxf(p.w, g.w);
      float cc = clamp0(cx2 - cx1) * clamp0(cy2 - cy1) + 1e-10f;
      float gi = 1.f - (iou - (cc - un) / cc);
      isum = (double)(gi * scale);
    }
    scale_arr[b * NL + l] = scale;
    jcls[b * NL + l] = j;
  }
  double r0 = block_red(isum, sred);
  double r1 = block_red(as, sred);
  if (threadIdx.x == 0) {
    int blk = blockIdx.y * gridDim.x + blockIdx.x;
    part_sc[blk * 2 + 0] = r0;
    part_sc[blk * 2 + 1] = r1;
  }
}

// ---------- Kernel C2: coalesced VFL-BCE (fast hw log), block partials ------
__global__ __launch_bounds__(256) void vfl_kernel(
    const float* __restrict__ ps, const float* __restrict__ scale_arr,
    const int* __restrict__ jcls, double* __restrict__ part_vfl)
{
  __shared__ double sred[4];
  const unsigned total4 = (unsigned)NB * NL * 20;  // 5,376,000 float4 units
  double cs = 0.0;
  for (unsigned gid = blockIdx.x * 256 + threadIdx.x; gid < total4;
       gid += (unsigned)gridDim.x * 256) {
    const unsigned row = gid / 20;
    const int c0 = (int)(gid % 20) * 4;
    float4 s4 = ((const float4*)ps)[gid];
    float scale = scale_arr[row];
    int j = jcls[row];
    float sv[4] = {s4.x, s4.y, s4.z, s4.w};
    float csum = 0.f;
#pragma unroll
    for (int u = 0; u < 4; ++u) {
      float s = sv[u];
      float pcl = fminf(fmaxf(s, 1e-9f), 1.f - 1e-9f);
      float lp1 = __log2f(1.f - pcl) * LN2F;   // log1p(-p), hw v_log_f32
      if (c0 + u == j)
        csum += -(scale * (__log2f(pcl) * LN2F) + (1.f - scale) * lp1) * scale;
      else
        csum += -lp1 * 0.75f * s * s;
    }
    cs += (double)csum;
  }
  double r = block_red(cs, sred);
  if (threadIdx.x == 0) part_vfl[blockIdx.x] = r;
}

// ---------------- Final: reduce partials, emit scalar ----------------------
__global__ __launch_bounds__(256) void fin_kernel(
    const double* __restrict__ part_vfl, const double* __restrict__ part_sc,
    float* __restrict__ out)
{
  __shared__ double sred[4];
  double cls = 0.0, isum = 0.0, as = 0.0;
  for (int i = threadIdx.x; i < VFL_BLOCKS; i += 256) cls += part_vfl[i];
  for (int i = threadIdx.x; i < SC_BLOCKS; i += 256) {
    isum += part_sc[i * 2 + 0];
    as   += part_sc[i * 2 + 1];
  }
  cls  = block_red(cls, sred);
  isum = block_red(isum, sred);
  as   = block_red(as, sred);
  if (threadIdx.x == 0) {
    double s = as > 1.0 ? as : 1.0;
    out[0] = (float)((cls + 2.5 * isum) / s);
  }
}

// ---------------------------------------------------------------------------
extern "C" void kernel_launch(void* const* d_in, const int* in_sizes, int n_in,
                              void* d_out, int out_size, void* d_ws, size_t ws_size,
                              hipStream_t stream) {
  const float* ps  = (const float*)d_in[0];   // [32,8400,80]
  const float* pbx = (const float*)d_in[1];   // [32,8400,4]
  const float* ap  = (const float*)d_in[2];   // [8400,2]
  const int*   gl  = (const int*)d_in[3];     // [32,100,1]
  const float* gtb = (const float*)d_in[4];   // [32,100,4]
  const float* pad = (const float*)d_in[5];   // [32,100,1]

  char* ws = (char*)d_ws;
  const size_t OFF_MAXM  = 0;                                 // 3200 u32
  const size_t OFF_MAXI  = OFF_MAXM + 4ul * NB * NGT;         // 3200 u32
  const size_t OFF_TOPK  = OFF_MAXI + 4ul * NB * NGT;         // 41600 i32
  const size_t OFF_NSTAR = OFF_TOPK + 4ul * NB * NGT * KTOP;  // 268800 i32
  const size_t OFF_ASTAR = OFF_NSTAR + 4ul * NB * NL;         // 268800 f32
  const size_t OFF_SCALE = OFF_ASTAR + 4ul * NB * NL;         // 268800 f32
  const size_t OFF_JCLS  = OFF_SCALE + 4ul * NB * NL;         // 268800 i32
  const size_t OFF_PVFL  = OFF_JCLS + 4ul * NB * NL;          // 2048 f64
  const size_t OFF_PSC   = OFF_PVFL + 8ul * VFL_BLOCKS;       // 2112 f64

  unsigned* maxm  = (unsigned*)(ws + OFF_MAXM);
  unsigned* maxi  = (unsigned*)(ws + OFF_MAXI);
  int*      topk  = (int*)(ws + OFF_TOPK);
  int*      nstar = (int*)(ws + OFF_NSTAR);
  float*    astar = (float*)(ws + OFF_ASTAR);
  float*    scale_arr = (float*)(ws + OFF_SCALE);
  int*      jcls  = (int*)(ws + OFF_JCLS);
  double*   pvfl  = (double*)(ws + OFF_PVFL);
  double*   psc   = (double*)(ws + OFF_PSC);

  hipMemsetAsync(ws, 0, OFF_TOPK, stream);  // zero maxm + maxi

  hipLaunchKernelGGL(topk_kernel, dim3(NB * NGT), dim3(256), 0, stream,
                     ps, pbx, gl, gtb, topk);
  hipLaunchKernelGGL(assign_kernel, dim3(SC_BLOCKS_X, NB), dim3(256), 0, stream,
                     ps, pbx, ap, gl, gtb, pad, topk, nstar, astar, maxm, maxi);
  hipLaunchKernelGGL(scale_kernel, dim3(SC_BLOCKS_X, NB), dim3(256), 0, stream,
                     pbx, gtb, gl, nstar, astar, maxm, maxi, scale_arr, jcls, psc);
  hipLaunchKernelGGL(vfl_kernel, dim3(VFL_BLOCKS), dim3(256), 0, stream,
                     ps, scale_arr, jcls, pvfl);
  hipLaunchKernelGGL(fin_kernel, dim3(1), dim3(256), 0, stream, pvfl, psc,
                     (float*)d_out);
}

// Round 10
// 88.379 us; speedup vs baseline: 2.4336x; 1.0603x over previous
//
#include <hip/hip_runtime.h>

#define NB 32
#define NGT 100
#define NL 8400
#define NC 80
#define KTOP 13
#define MAXC 640  // >= max enumerated candidates per (b,n) (bound ~531)
#define VFL_BLOCKS 2048
#define SC_BLOCKS_X 33   // ceil(8400/256)
#define SC_BLOCKS (SC_BLOCKS_X * NB)
#define LN2F 0.6931471805599453f

__device__ __forceinline__ float clamp0(float x) { return fmaxf(x, 0.f); }

__device__ __forceinline__ unsigned long long mkkey(float v, unsigned lowk) {
  return ((unsigned long long)__float_as_uint(v) << 32) | (unsigned long long)lowk;
}

// Block-reduce a double (256 threads); result valid on thread 0.
__device__ __forceinline__ double block_red(double v, double* sred) {
  for (int off = 32; off > 0; off >>= 1) v += __shfl_down(v, off);
  int wid = threadIdx.x >> 6;
  if ((threadIdx.x & 63) == 0) sred[wid] = v;
  __syncthreads();
  double r = 0.0;
  if (threadIdx.x == 0) r = sred[0] + sred[1] + sred[2] + sred[3];
  __syncthreads();
  return r;
}

// conservative grid range for centers (c+0.5)*s inside (lo, hi)
__device__ __forceinline__ void grange(float lo, float hi, float s, int G,
                                       int& a0, int& an) {
  int c0 = max(0, (int)floorf(lo / s - 0.5f));
  int c1 = min(G - 1, (int)ceilf(hi / s - 0.5f));
  a0 = c0;
  an = max(0, c1 - c0 + 1);
}

// ---- Kernel A: candidate ENUMERATION -> wave-0 top-13; also zeroes the ----
// ---- per-(b,n) atomicMax slots consumed by assign_kernel (stream order) ---
__global__ __launch_bounds__(256) void topk_kernel(
    const float* __restrict__ ps, const float* __restrict__ pb,
    const int* __restrict__ gl, const float* __restrict__ gtb,
    int* __restrict__ topk_out, unsigned* __restrict__ maxm,
    unsigned* __restrict__ maxi)
{
  __shared__ unsigned long long cand[MAXC];
  __shared__ unsigned zmask[2];
  __shared__ int cnt;
  const int bn = blockIdx.x;
  const int b = bn / NGT;
  const float gx1 = gtb[bn * 4 + 0], gy1 = gtb[bn * 4 + 1];
  const float gx2 = gtb[bn * 4 + 2], gy2 = gtb[bn * 4 + 3];
  const int cls = gl[bn];
  const float ga = clamp0(gx2 - gx1) * clamp0(gy2 - gy1);
  const float4* pbb = (const float4*)pb + (size_t)b * NL;
  const float* psb = ps + (size_t)b * NL * NC;

  if (threadIdx.x == 0) {
    cnt = 0;
    maxm[bn] = 0u;   // replaces host-side memset (assign runs after us)
    maxi[bn] = 0u;
  }

  // Pass A (wave 0): zero-metric mask for anchors 0..63 (row 0 of s8 grid).
  if (threadIdx.x < 64) {
    const int l = (int)threadIdx.x;
    float4 p = pbb[l];
    float x = ((float)l + 0.5f) * 8.0f, y = 4.0f;
    float ox = fminf(p.z, gx2) - fmaxf(p.x, gx1);
    float oy = fminf(p.w, gy2) - fmaxf(p.y, gy1);
    float ov = clamp0(ox) * clamp0(oy);
    float pa = clamp0(p.z - p.x) * clamp0(p.w - p.y);
    float iou = ov * __builtin_amdgcn_rcpf(ga + pa - ov + 1e-9f);
    bool ins = fminf(fminf(x - gx1, y - gy1),
                     fminf(gx2 - x, gy2 - y)) > 1e-9f;
    bool pos = ins && (iou > 0.f);
    unsigned long long zm = __ballot(!pos);
    if (threadIdx.x == 0) { zmask[0] = (unsigned)zm; zmask[1] = (unsigned)(zm >> 32); }
  }
  __syncthreads();

  // Candidate windows per scale (identical scalars on all threads).
  int c8, nc8, r8, nr8, c16, nc16, r16, nr16, c32, nc32, r32, nr32;
  grange(gx1, gx2, 8.f, 80, c8, nc8);   grange(gy1, gy2, 8.f, 80, r8, nr8);
  grange(gx1, gx2, 16.f, 40, c16, nc16); grange(gy1, gy2, 16.f, 40, r16, nr16);
  grange(gx1, gx2, 32.f, 20, c32, nc32); grange(gy1, gy2, 32.f, 20, r32, nr32);
  const int t8 = nc8 * nr8, t16 = nc16 * nr16, t32 = nc32 * nr32;
  const int total = t8 + t16 + t32;

  // Phase 1: test enumerated candidates; positives -> LDS list.
  for (int idx = threadIdx.x; idx < total; idx += 256) {
    int l; float x, y;
    if (idx < t8) {
      int q = idx / nc8, cc = c8 + (idx - q * nc8), rr = r8 + q;
      l = rr * 80 + cc; x = ((float)cc + 0.5f) * 8.f; y = ((float)rr + 0.5f) * 8.f;
    } else if (idx < t8 + t16) {
      int id = idx - t8;
      int q = id / nc16, cc = c16 + (id - q * nc16), rr = r16 + q;
      l = 6400 + rr * 40 + cc; x = ((float)cc + 0.5f) * 16.f; y = ((float)rr + 0.5f) * 16.f;
    } else {
      int id = idx - t8 - t16;
      int q = id / nc32, cc = c32 + (id - q * nc32), rr = r32 + q;
      l = 8000 + rr * 20 + cc; x = ((float)cc + 0.5f) * 32.f; y = ((float)rr + 0.5f) * 32.f;
    }
    float4 p = pbb[l];
    float ox = fminf(p.z, gx2) - fmaxf(p.x, gx1);
    float oy = fminf(p.w, gy2) - fmaxf(p.y, gy1);
    float ov = clamp0(ox) * clamp0(oy);
    float pa = clamp0(p.z - p.x) * clamp0(p.w - p.y);
    float iou = ov * __builtin_amdgcn_rcpf(ga + pa - ov + 1e-9f);
    bool ins = fminf(fminf(x - gx1, y - gy1),
                     fminf(gx2 - x, gy2 - y)) > 1e-9f;
    if (ins && iou > 0.f) {
      int id2 = atomicAdd(&cnt, 1);
      if (id2 < MAXC)
        cand[id2] = ((unsigned long long)__float_as_uint(iou) << 32) |
                    (unsigned long long)(0xFFFFFFFFu - (unsigned)l);
    }
  }
  __syncthreads();

  // Phase 2: gather score for positives; finalize key v = sc * iou^6.
  const int n = min(cnt, MAXC);
  for (int idx = threadIdx.x; idx < n; idx += 256) {
    unsigned long long e = cand[idx];
    unsigned lowk = (unsigned)e;
    int l = (int)(0xFFFFFFFFu - lowk);
    float iou = __uint_as_float((unsigned)(e >> 32));
    float sc = psb[(size_t)l * NC + cls];
    float i2 = iou * iou;
    float v = sc * i2 * i2 * i2;
    if (v > 0.f) {
      cand[idx] = mkkey(v, lowk);
    } else {               // underflow: metric exactly 0 -> zero-tie set
      cand[idx] = 0ull;
      if (l < 64) atomicOr(&zmask[l >> 5], 1u << (l & 31));
    }
  }
  __syncthreads();

  // Merge: wave 0 only, no barriers. Lanes hold <=10 candidates in regs.
  if (threadIdx.x < 64) {
    unsigned long long c[MAXC / 64];
#pragma unroll
    for (int j = 0; j < MAXC / 64; ++j) {
      int idx = (int)threadIdx.x + 64 * j;
      c[j] = (idx < n) ? cand[idx] : 0ull;
    }
    unsigned long long zm = ((unsigned long long)zmask[1] << 32) | zmask[0];
    for (int k = 0; k < KTOP; ++k) {
      unsigned long long m = c[0];
#pragma unroll
      for (int j = 1; j < MAXC / 64; ++j) m = (c[j] > m) ? c[j] : m;
      for (int off = 1; off < 64; off <<= 1) {
        unsigned long long o = __shfl_xor(m, off);
        m = (o > m) ? o : m;
      }
      int outl;
      if (m != 0ull) {  // a positive candidate wins
#pragma unroll
        for (int j = 0; j < MAXC / 64; ++j)
          if (c[j] == m) c[j] = 0ull;
        outl = (int)(0xFFFFFFFFu - (unsigned)(m & 0xFFFFFFFFull));
      } else {          // pad with smallest-index zero-metric anchor
        outl = (int)(__ffsll((long long)zm) - 1);
        zm &= zm - 1;
      }
      if (threadIdx.x == 0) topk_out[bn * KTOP + k] = outl;
    }
  }
}

// ------------- Kernel B: per-(b,l) assignment (n*, align*, iou*) -------------
__global__ __launch_bounds__(256) void assign_kernel(
    const float* __restrict__ ps, const float* __restrict__ pb,
    const float* __restrict__ ap, const int* __restrict__ gl,
    const float* __restrict__ gtb, const float* __restrict__ pad,
    const int* __restrict__ topk, int* __restrict__ nstar,
    float* __restrict__ astar, unsigned* __restrict__ maxm,
    unsigned* __restrict__ maxi)
{
  __shared__ float4 sgt[NGT];
  __shared__ int sgl[NGT];
  __shared__ float spad[NGT];
  __shared__ int stopk[NGT * KTOP];
  const int b = blockIdx.y;
  for (int i = threadIdx.x; i < NGT; i += 256) {
    sgt[i] = ((const float4*)gtb)[b * NGT + i];
    sgl[i] = gl[b * NGT + i];
    spad[i] = pad[b * NGT + i];
  }
  for (int i = threadIdx.x; i < NGT * KTOP; i += 256)
    stopk[i] = topk[b * NGT * KTOP + i];
  __syncthreads();

  const int l = blockIdx.x * 256 + threadIdx.x;
  if (l >= NL) return;

  float4 p = ((const float4*)pb)[(size_t)b * NL + l];
  float2 a = ((const float2*)ap)[l];
  float pa = clamp0(p.z - p.x) * clamp0(p.w - p.y);

  int mps = 0, n_single = -1, max_n = 0;
  float iou_single = 0.f, max_iou = -1.f;
  for (int n = 0; n < NGT; ++n) {
    float4 g = sgt[n];
    float ox = fminf(p.z, g.z) - fmaxf(p.x, g.x);
    float oy = fminf(p.w, g.w) - fmaxf(p.y, g.y);
    float ov = clamp0(ox) * clamp0(oy);
    float ga = clamp0(g.z - g.x) * clamp0(g.w - g.y);
    float iou = ov / (ga + pa - ov + 1e-9f);
    if (iou > max_iou) { max_iou = iou; max_n = n; }  // argmax over ALL n (incl. pad)
    bool ins = fminf(fminf(a.x - g.x, a.y - g.y),
                     fminf(g.z - a.x, g.w - a.y)) > 1e-9f;
    if (ins && spad[n] != 0.f) {
      bool hit = false;
#pragma unroll
      for (int k = 0; k < KTOP; ++k) hit |= (stopk[n * KTOP + k] == l);
      if (hit) { mps++; n_single = n; iou_single = iou; }
    }
  }

  int ns; float iou_s;
  if (mps == 0)      { ns = -1;       iou_s = 0.f; }
  else if (mps == 1) { ns = n_single; iou_s = iou_single; }
  else               { ns = max_n;    iou_s = max_iou; }  // is_max_iou replacement

  float al_s = 0.f;
  if (ns >= 0) {
    float sc = ps[((size_t)b * NL + l) * NC + sgl[ns]];
    float i2 = iou_s * iou_s;
    al_s = sc * i2 * i2 * i2;
    atomicMax(&maxm[b * NGT + ns], __float_as_uint(al_s));
    atomicMax(&maxi[b * NGT + ns], __float_as_uint(iou_s));
  }
  nstar[b * NL + l] = ns;
  astar[b * NL + l] = al_s;
}

// ------- Kernel C1: per-(b,l) scale/class + GIoU term; per-block partials ---
__global__ __launch_bounds__(256) void scale_kernel(
    const float* __restrict__ pb, const float* __restrict__ gtb,
    const int* __restrict__ gl, const int* __restrict__ nstar,
    const float* __restrict__ astar, const unsigned* __restrict__ maxm,
    const unsigned* __restrict__ maxi, float* __restrict__ scale_arr,
    int* __restrict__ jcls, double* __restrict__ part_sc)
{
  __shared__ double sred[4];
  const int b = blockIdx.y;
  const int l = blockIdx.x * 256 + threadIdx.x;
  double isum = 0.0, as = 0.0;
  if (l < NL) {
    int ns = nstar[b * NL + l];
    float scale = 0.f;
    int j = NC;
    if (ns >= 0) {
      float mm = __uint_as_float(maxm[b * NGT + ns]);
      float mi = __uint_as_float(maxi[b * NGT + ns]);
      scale = astar[b * NL + l] / (mm + 1e-9f) * mi;
      j = gl[b * NGT + ns];
      as = (double)scale;
      float4 p = ((const float4*)pb)[(size_t)b * NL + l];
      float4 g = ((const float4*)gtb)[b * NGT + ns];
      float x1 = fmaxf(p.x, g.x), y1 = fmaxf(p.y, g.y);
      float x2 = fminf(p.z, g.z), y2 = fminf(p.w, g.w);
      float ov = clamp0(x2 - x1) * clamp0(y2 - y1);
      float pa = clamp0(p.z - p.x) * clamp0(p.w - p.y);
      float ga = clamp0(g.z - g.x) * clamp0(g.w - g.y);
      float un = pa + ga - ov + 1e-10f;
      float iou = ov / un;
      float cx1 = fminf(p.x, g.x), cy1 = fminf(p.y, g.y);
      float cx2 = fmaxf(p.z, g.z), cy2 = fmaxf(p.w, g.w);
      float cc = clamp0(cx2 - cx1) * clamp0(cy2 - cy1) + 1e-10f;
      float gi = 1.f - (iou - (cc - un) / cc);
      isum = (double)(gi * scale);
    }
    scale_arr[b * NL + l] = scale;
    jcls[b * NL + l] = j;
  }
  double r0 = block_red(isum, sred);
  double r1 = block_red(as, sred);
  if (threadIdx.x == 0) {
    int blk = blockIdx.y * gridDim.x + blockIdx.x;
    part_sc[blk * 2 + 0] = r0;
    part_sc[blk * 2 + 1] = r1;
  }
}

// ---------- Kernel C2: coalesced VFL-BCE (fast hw log), block partials ------
__global__ __launch_bounds__(256) void vfl_kernel(
    const float* __restrict__ ps, const float* __restrict__ scale_arr,
    const int* __restrict__ jcls, double* __restrict__ part_vfl)
{
  __shared__ double sred[4];
  const unsigned total4 = (unsigned)NB * NL * 20;  // 5,376,000 float4 units
  double cs = 0.0;
  for (unsigned gid = blockIdx.x * 256 + threadIdx.x; gid < total4;
       gid += (unsigned)gridDim.x * 256) {
    const unsigned row = gid / 20;
    const int c0 = (int)(gid % 20) * 4;
    float4 s4 = ((const float4*)ps)[gid];
    float scale = scale_arr[row];
    int j = jcls[row];
    float sv[4] = {s4.x, s4.y, s4.z, s4.w};
    float csum = 0.f;
#pragma unroll
    for (int u = 0; u < 4; ++u) {
      float s = sv[u];
      float pcl = fminf(fmaxf(s, 1e-9f), 1.f - 1e-9f);
      float lp1 = __log2f(1.f - pcl) * LN2F;   // log1p(-p), hw v_log_f32
      if (c0 + u == j)
        csum += -(scale * (__log2f(pcl) * LN2F) + (1.f - scale) * lp1) * scale;
      else
        csum += -lp1 * 0.75f * s * s;
    }
    cs += (double)csum;
  }
  double r = block_red(cs, sred);
  if (threadIdx.x == 0) part_vfl[blockIdx.x] = r;
}

// ---------------- Final: reduce partials, emit scalar ----------------------
__global__ __launch_bounds__(256) void fin_kernel(
    const double* __restrict__ part_vfl, const double* __restrict__ part_sc,
    float* __restrict__ out)
{
  __shared__ double sred[4];
  double cls = 0.0, isum = 0.0, as = 0.0;
  for (int i = threadIdx.x; i < VFL_BLOCKS; i += 256) cls += part_vfl[i];
  for (int i = threadIdx.x; i < SC_BLOCKS; i += 256) {
    isum += part_sc[i * 2 + 0];
    as   += part_sc[i * 2 + 1];
  }
  cls  = block_red(cls, sred);
  isum = block_red(isum, sred);
  as   = block_red(as, sred);
  if (threadIdx.x == 0) {
    double s = as > 1.0 ? as : 1.0;
    out[0] = (float)((cls + 2.5 * isum) / s);
  }
}

// ---------------------------------------------------------------------------
extern "C" void kernel_launch(void* const* d_in, const int* in_sizes, int n_in,
                              void* d_out, int out_size, void* d_ws, size_t ws_size,
                              hipStream_t stream) {
  const float* ps  = (const float*)d_in[0];   // [32,8400,80]
  const float* pbx = (const float*)d_in[1];   // [32,8400,4]
  const float* ap  = (const float*)d_in[2];   // [8400,2]
  const int*   gl  = (const int*)d_in[3];     // [32,100,1]
  const float* gtb = (const float*)d_in[4];   // [32,100,4]
  const float* pad = (const float*)d_in[5];   // [32,100,1]

  char* ws = (char*)d_ws;
  const size_t OFF_MAXM  = 0;                                 // 3200 u32
  const size_t OFF_MAXI  = OFF_MAXM + 4ul * NB * NGT;         // 3200 u32
  const size_t OFF_TOPK  = OFF_MAXI + 4ul * NB * NGT;         // 41600 i32
  const size_t OFF_NSTAR = OFF_TOPK + 4ul * NB * NGT * KTOP;  // 268800 i32
  const size_t OFF_ASTAR = OFF_NSTAR + 4ul * NB * NL;         // 268800 f32
  const size_t OFF_SCALE = OFF_ASTAR + 4ul * NB * NL;         // 268800 f32
  const size_t OFF_JCLS  = OFF_SCALE + 4ul * NB * NL;         // 268800 i32
  const size_t OFF_PVFL  = OFF_JCLS + 4ul * NB * NL;          // 2048 f64
  const size_t OFF_PSC   = OFF_PVFL + 8ul * VFL_BLOCKS;       // 2112 f64

  unsigned* maxm  = (unsigned*)(ws + OFF_MAXM);
  unsigned* maxi  = (unsigned*)(ws + OFF_MAXI);
  int*      topk  = (int*)(ws + OFF_TOPK);
  int*      nstar = (int*)(ws + OFF_NSTAR);
  float*    astar = (float*)(ws + OFF_ASTAR);
  float*    scale_arr = (float*)(ws + OFF_SCALE);
  int*      jcls  = (int*)(ws + OFF_JCLS);
  double*   pvfl  = (double*)(ws + OFF_PVFL);
  double*   psc   = (double*)(ws + OFF_PSC);

  // NOTE: no hipMemsetAsync — topk_kernel zeroes maxm/maxi in-kernel
  // (one slot per block, strictly before assign_kernel in stream order).

  hipLaunchKernelGGL(topk_kernel, dim3(NB * NGT), dim3(256), 0, stream,
                     ps, pbx, gl, gtb, topk, maxm, maxi);
  hipLaunchKernelGGL(assign_kernel, dim3(SC_BLOCKS_X, NB), dim3(256), 0, stream,
                     ps, pbx, ap, gl, gtb, pad, topk, nstar, astar, maxm, maxi);
  hipLaunchKernelGGL(scale_kernel, dim3(SC_BLOCKS_X, NB), dim3(256), 0, stream,
                     pbx, gtb, gl, nstar, astar, maxm, maxi, scale_arr, jcls, psc);
  hipLaunchKernelGGL(vfl_kernel, dim3(VFL_BLOCKS), dim3(256), 0, stream,
                     ps, scale_arr, jcls, pvfl);
  hipLaunchKernelGGL(fin_kernel, dim3(1), dim3(256), 0, stream, pvfl, psc,
                     (float*)d_out);
}